// Round 1
// baseline (6645.302 us; speedup 1.0000x reference)
//
#include <hip/hip_runtime.h>
#include <hip/hip_bf16.h>
#include <hip/hip_cooperative_groups.h>

namespace cg = cooperative_groups;

typedef __bf16 bf16x8 __attribute__((ext_vector_type(8)));
typedef float floatx4 __attribute__((ext_vector_type(4)));

#define GLD_LDS16(g, s)                                              \
  __builtin_amdgcn_global_load_lds(                                  \
      (__attribute__((address_space(1))) void*)(g),                  \
      (__attribute__((address_space(3))) void*)(s), 16, 0, 0)

#define MFMA16(a, b, c) __builtin_amdgcn_mfma_f32_16x16x32_bf16(a, b, c, 0, 0, 0)

constexpr int B_ = 128, S_ = 256, E_ = 512, H_ = 1024, V_ = 2048;
constexpr int KC_ = E_ + H_;

// ---- dtype detect (bf16 vs fp32 inputs) ----
__global__ void k_detect(const unsigned short* __restrict__ emb,
                         int* __restrict__ flag) {
  __shared__ int cnt;
  if (threadIdx.x == 0) cnt = 0;
  __syncthreads();
  int local = 0;
  for (int i = threadIdx.x; i < 32768; i += 256) {
    unsigned int u = ((unsigned int)emb[i]) << 16;
    float v = __uint_as_float(u);
    if (!(fabsf(v) < 1.0f)) local++;
  }
  atomicAdd(&cnt, local);
  __syncthreads();
  if (threadIdx.x == 0) flag[0] = (cnt > 256) ? 1 : 0;
}

// ---- biases -> fp32 ws ----
__global__ void k_bias(const void* __restrict__ bfv, const void* __restrict__ bbv,
                       const void* __restrict__ bdv, float* __restrict__ biasws,
                       const int* __restrict__ flag) {
  bool f32 = flag[0] != 0;
  int i = blockIdx.x * 256 + threadIdx.x;
  if (i >= 10240) return;
  const void* src;
  int off;
  if (i < 4096) { src = bfv; off = i; }
  else if (i < 8192) { src = bbv; off = i - 4096; }
  else { src = bdv; off = i - 8192; }
  float v = f32 ? ((const float*)src)[off]
                : __bfloat162float(((const __hip_bfloat16*)src)[off]);
  biasws[i] = v;
}

// ---- gather ----
__global__ void k_gather(const int* __restrict__ tokens, const void* __restrict__ emb,
                         __hip_bfloat16* __restrict__ xt,
                         const int* __restrict__ flag) {
  bool f32 = flag[0] != 0;
  int idx = blockIdx.x * 256 + threadIdx.x;
  int e8 = idx & 63;
  int sb = idx >> 6;
  int s = sb >> 7;
  int b = sb & 127;
  int tok = tokens[b * S_ + s];
  uint4* dst = (uint4*)(xt + (size_t)sb * E_) + e8;
  if (f32) {
    const float* src = (const float*)emb + (size_t)tok * E_ + e8 * 8;
    float4 lo = ((const float4*)src)[0];
    float4 hi = ((const float4*)src)[1];
    __hip_bfloat16 v[8];
    v[0] = __float2bfloat16(lo.x); v[1] = __float2bfloat16(lo.y);
    v[2] = __float2bfloat16(lo.z); v[3] = __float2bfloat16(lo.w);
    v[4] = __float2bfloat16(hi.x); v[5] = __float2bfloat16(hi.y);
    v[6] = __float2bfloat16(hi.z); v[7] = __float2bfloat16(hi.w);
    *dst = *(const uint4*)v;
  } else {
    *dst = ((const uint4*)((const __hip_bfloat16*)emb + (size_t)tok * E_))[e8];
  }
}

// ---- transpose ----
__global__ void k_transpose(const void* __restrict__ in, int K, int N,
                            __hip_bfloat16* __restrict__ out, int ostride,
                            int ocol, const int* __restrict__ flag) {
  bool f32 = flag[0] != 0;
  __shared__ __hip_bfloat16 tile[64][65];
  int n0 = blockIdx.x * 64, k0 = blockIdx.y * 64;
  for (int i = 0; i < 16; ++i) {
    int flat = i * 256 + threadIdx.x;
    int kk = flat >> 6, nn = flat & 63;
    size_t off = (size_t)(k0 + kk) * N + n0 + nn;
    tile[kk][nn] = f32 ? __float2bfloat16(((const float*)in)[off])
                       : ((const __hip_bfloat16*)in)[off];
  }
  __syncthreads();
  for (int i = 0; i < 16; ++i) {
    int flat = i * 256 + threadIdx.x;
    int nn = flat >> 6, kk = flat & 63;
    out[(size_t)(n0 + nn) * ostride + ocol + k0 + kk] = tile[kk][nn];
  }
}

// ---- persistent bidirectional LSTM, weight-stationary, 512 thr/block ----
// 256 blocks: 0..127 fwd (tanh), 128..255 bwd (relu). Block owns 8 h-units
// (N=32 z-cols). Weights [32][1536] in LDS fragment order. 8 waves, wave
// tile M16xN32. Slot-array barrier; x-part of step t+1 computed after
// signaling step t (hides barrier wait).
__global__ void __launch_bounds__(512, 2)
k_lstm(const __hip_bfloat16* __restrict__ xt,
       const __hip_bfloat16* __restrict__ WTf,
       const __hip_bfloat16* __restrict__ WTb,
       const float* __restrict__ biasf, const float* __restrict__ biasb,
       __hip_bfloat16* __restrict__ hcat, int* __restrict__ slots0,
       int* __restrict__ slots1) {
  extern __shared__ __align__(16) unsigned char smem[];
  __hip_bfloat16* Blds = (__hip_bfloat16*)smem;  // 96 frags x 1KB
  float* ztf = (float*)(smem + 98304);           // 16 frags x 1KB

  const int tid = threadIdx.x, lane = tid & 63, wave = tid >> 6;
  const int dir = blockIdx.x >> 7;
  const int nb = blockIdx.x & 127;
  const int j0 = nb * 8;
  const __hip_bfloat16* WT = dir ? WTb : WTf;
  const float* bias = dir ? biasb : biasf;
  int* slots = dir ? slots1 : slots0;

  // stage weights (fragment order); 12 frags per wave
  for (int f = wave; f < 96; f += 8) {
    int kc = f >> 1, j = f & 1;
    int c = j * 16 + (lane & 15);
    int row = (c >> 3) * H_ + j0 + (c & 7);
    const __hip_bfloat16* src =
        WT + (size_t)row * KC_ + kc * 32 + ((lane >> 4) * 8);
    GLD_LDS16(src, (char*)Blds + (size_t)f * 1024);
  }

  const int jj = tid & 7;
  const int erow = tid >> 3;  // 0..63
  const float bi = bias[j0 + jj];
  const float bf2 = bias[H_ + j0 + jj];
  const float bg = bias[2 * H_ + j0 + jj];
  const float bo = bias[3 * H_ + j0 + jj];
  float creg[2] = {0.f, 0.f};

  const int m0 = wave * 16 + (lane & 15);
  const int k8 = (lane >> 4) * 8;
  __syncthreads();  // drains weight staging

  floatx4 acc[2];
  {  // x-part for t=0
    const int t_in = dir ? (S_ - 1) : 0;
    const __hip_bfloat16* xb =
        xt + (size_t)t_in * B_ * E_ + (size_t)m0 * E_ + k8;
    acc[0] = (floatx4)(0.f);
    acc[1] = (floatx4)(0.f);
#pragma unroll 8
    for (int kc = 0; kc < 16; ++kc) {
      bf16x8 a = *(const bf16x8*)(xb + kc * 32);
      bf16x8 b0 = *(const bf16x8*)((char*)Blds + (kc * 2 + 0) * 1024 + lane * 16);
      bf16x8 b1 = *(const bf16x8*)((char*)Blds + (kc * 2 + 1) * 1024 + lane * 16);
      acc[0] = MFMA16(a, b0, acc[0]);
      acc[1] = MFMA16(a, b1, acc[1]);
    }
  }

  for (int t = 0; t < S_; ++t) {
    const int t_in = dir ? (S_ - 1 - t) : t;
    const int t_prev = dir ? (t_in + 1) : (t_in - 1);

    if (t > 0) {
      if (wave == 0) {  // wait: all 128 slots >= t (parallel poll)
        while (true) {
          int v0 = __hip_atomic_load(slots + lane, __ATOMIC_RELAXED,
                                     __HIP_MEMORY_SCOPE_AGENT);
          int v1 = __hip_atomic_load(slots + 64 + lane, __ATOMIC_RELAXED,
                                     __HIP_MEMORY_SCOPE_AGENT);
          if (__all(v0 >= t && v1 >= t)) break;
          __builtin_amdgcn_s_sleep(1);
        }
        __threadfence();  // acquire: invalidate stale caches
      }
      __syncthreads();
      const __hip_bfloat16* hb = hcat + (size_t)t_prev * B_ * 2 * H_ +
                                 dir * H_ + (size_t)m0 * 2 * H_ + k8;
#pragma unroll 8
      for (int kc = 0; kc < 32; ++kc) {
        bf16x8 a = *(const bf16x8*)(hb + (size_t)kc * 32);
        bf16x8 b0 =
            *(const bf16x8*)((char*)Blds + ((16 + kc) * 2 + 0) * 1024 + lane * 16);
        bf16x8 b1 =
            *(const bf16x8*)((char*)Blds + ((16 + kc) * 2 + 1) * 1024 + lane * 16);
        acc[0] = MFMA16(a, b0, acc[0]);
        acc[1] = MFMA16(a, b1, acc[1]);
      }
    }

    // acc -> LDS fragment order
    *(floatx4*)((char*)ztf + (wave * 2 + 0) * 1024 + lane * 16) = acc[0];
    *(floatx4*)((char*)ztf + (wave * 2 + 1) * 1024 + lane * 16) = acc[1];
    __syncthreads();

    __hip_bfloat16* hout =
        hcat + (size_t)t_in * B_ * 2 * H_ + dir * H_ + j0 + jj;
#pragma unroll
    for (int q = 0; q < 2; ++q) {
      int b_ = erow + q * 64;
      int w = b_ >> 4, mm = b_ & 15;
      float z[4];
#pragma unroll
      for (int g = 0; g < 4; ++g) {
        int c = g * 8 + jj;
        z[g] = ztf[(w * 2 + (c >> 4)) * 256 + ((c & 15) + 16 * (mm >> 2)) * 4 +
                   (mm & 3)];
      }
      float iv = 1.f / (1.f + __expf(-(z[0] + bi)));
      float fv = 1.f / (1.f + __expf(-(z[1] + bf2)));
      float ov = 1.f / (1.f + __expf(-(z[3] + bo)));
      float zg = z[2] + bg;
      float gv = dir ? fmaxf(zg, 0.f) : (1.f - 2.f / (__expf(2.f * zg) + 1.f));
      float c_ = fv * creg[q] + iv * gv;
      creg[q] = c_;
      float hv = dir ? (ov * fmaxf(c_, 0.f))
                     : (ov * (1.f - 2.f / (__expf(2.f * c_) + 1.f)));
      hout[(size_t)b_ * 2 * H_] = __float2bfloat16(hv);
    }
    __syncthreads();  // all h stores drained to L2 (vmcnt(0) at barrier)

    if (tid == 0) {
      __threadfence();  // release: L2 writeback for cross-XCD visibility
      __hip_atomic_store(slots + nb, t + 1, __ATOMIC_RELAXED,
                         __HIP_MEMORY_SCOPE_AGENT);
    }

    if (t + 1 < S_) {  // x-part for next step: hides barrier wait
      const int tn = dir ? (S_ - 2 - t) : (t + 1);
      const __hip_bfloat16* xb =
          xt + (size_t)tn * B_ * E_ + (size_t)m0 * E_ + k8;
      acc[0] = (floatx4)(0.f);
      acc[1] = (floatx4)(0.f);
#pragma unroll 8
      for (int kc = 0; kc < 16; ++kc) {
        bf16x8 a = *(const bf16x8*)(xb + kc * 32);
        bf16x8 b0 =
            *(const bf16x8*)((char*)Blds + (kc * 2 + 0) * 1024 + lane * 16);
        bf16x8 b1 =
            *(const bf16x8*)((char*)Blds + (kc * 2 + 1) * 1024 + lane * 16);
        acc[0] = MFMA16(a, b0, acc[0]);
        acc[1] = MFMA16(a, b1, acc[1]);
      }
    }
  }
}

// ---- dense: out[b][s][v] = hcat[s][b][:] @ Wd + bd ----
__global__ void __launch_bounds__(256, 1)
k_dense(const __hip_bfloat16* __restrict__ hcat,
        const __hip_bfloat16* __restrict__ WdT, const float* __restrict__ bd,
        void* __restrict__ outv, const int* __restrict__ flag) {
  bool f32 = flag[0] != 0;
  __shared__ __align__(16) unsigned char smem[16384];
  __hip_bfloat16* At = (__hip_bfloat16*)smem;
  __hip_bfloat16* Bt = (__hip_bfloat16*)(smem + 8192);
  const int tid = threadIdx.x, lane = tid & 63, wave = tid >> 6;
  const int wr = wave >> 1, wc = wave & 1;
  const int r0 = blockIdx.x * 128;
  const int n0 = blockIdx.y * 128;

  floatx4 acc[4][4] = {};
  int arow[2], akoff[2];
  for (int q = 0; q < 2; ++q) {
    int flat = (wave * 2 + q) * 1024 + lane * 16;
    arow[q] = flat >> 6;
    akoff[q] = (flat & 63) >> 1;
  }

  for (int kc = 0; kc < 64; ++kc) {
    for (int q = 0; q < 2; ++q) {
      const __hip_bfloat16* srcA =
          hcat + (size_t)(r0 + arow[q]) * 2048 + kc * 32 + akoff[q];
      GLD_LDS16(srcA, At + (wave * 2 + q) * 512);
      const __hip_bfloat16* srcB =
          WdT + (size_t)(n0 + arow[q]) * 2048 + kc * 32 + akoff[q];
      GLD_LDS16(srcB, Bt + (wave * 2 + q) * 512);
    }
    __syncthreads();
    bf16x8 a[4], b[4];
    const int k8 = (lane >> 4) * 8;
    for (int i = 0; i < 4; ++i) {
      int m = wr * 64 + i * 16 + (lane & 15);
      a[i] = *(const bf16x8*)((const char*)At + m * 64 + k8 * 2);
    }
    for (int j = 0; j < 4; ++j) {
      int n = wc * 64 + j * 16 + (lane & 15);
      b[j] = *(const bf16x8*)((const char*)Bt + n * 64 + k8 * 2);
    }
    for (int i = 0; i < 4; ++i)
      for (int j = 0; j < 4; ++j)
        acc[i][j] = MFMA16(a[i], b[j], acc[i][j]);
    __syncthreads();
  }

  for (int j = 0; j < 4; ++j) {
    int n = n0 + wc * 64 + j * 16 + (lane & 15);
    float bdv = bd[n];
    for (int i = 0; i < 4; ++i)
      for (int r = 0; r < 4; ++r) {
        int m = wr * 64 + i * 16 + (lane >> 4) * 4 + r;
        int row = r0 + m;
        int s = row >> 7, b_ = row & 127;
        size_t off = (size_t)b_ * S_ * V_ + (size_t)s * V_ + n;
        float val = acc[i][j][r] + bdv;
        if (f32)
          ((float*)outv)[off] = val;
        else
          ((__hip_bfloat16*)outv)[off] = __float2bfloat16(val);
      }
  }
}

extern "C" void kernel_launch(void* const* d_in, const int* in_sizes, int n_in,
                              void* d_out, int out_size, void* d_ws,
                              size_t ws_size, hipStream_t stream) {
  const int* tokens = (const int*)d_in[0];
  const void* emb = d_in[1];
  const void* Wf = d_in[2];
  const void* Uf = d_in[3];
  const void* bfv = d_in[4];
  const void* Wb = d_in[5];
  const void* Ub = d_in[6];
  const void* bbv = d_in[7];
  const void* Wd = d_in[8];
  const void* bd = d_in[9];

  char* ws = (char*)d_ws;
  int* flag = (int*)ws;                      // 4B @ 0
  int* slots0 = (int*)(ws + 128);            // 128 ints
  int* slots1 = (int*)(ws + 1152);           // 128 ints
  float* biasws = (float*)(ws + 4096);       // 10240 f32
  __hip_bfloat16* WTf = (__hip_bfloat16*)(ws + 4096 + 40960);
  __hip_bfloat16* WTb = WTf + (size_t)4096 * 1536;
  __hip_bfloat16* WdT = WTb + (size_t)4096 * 1536;
  __hip_bfloat16* xt = WdT + (size_t)2048 * 2048;
  __hip_bfloat16* hcat = xt + (size_t)S_ * B_ * E_;  // [256][128][2048]

  hipMemsetAsync(ws + 128, 0, 4096 - 128, stream);
  k_detect<<<1, 256, 0, stream>>>((const unsigned short*)emb, flag);
  k_bias<<<40, 256, 0, stream>>>(bfv, bbv, bd, biasws, flag);
  k_gather<<<8192, 256, 0, stream>>>(tokens, emb, xt, flag);
  k_transpose<<<dim3(64, 8), 256, 0, stream>>>(Wf, 512, 4096, WTf, KC_, 0, flag);
  k_transpose<<<dim3(64, 16), 256, 0, stream>>>(Uf, 1024, 4096, WTf, KC_, 512, flag);
  k_transpose<<<dim3(64, 8), 256, 0, stream>>>(Wb, 512, 4096, WTb, KC_, 0, flag);
  k_transpose<<<dim3(64, 16), 256, 0, stream>>>(Ub, 1024, 4096, WTb, KC_, 512, flag);
  k_transpose<<<dim3(32, 32), 256, 0, stream>>>(Wd, 2048, 2048, WdT, 2048, 0, flag);

  float* biasf_ws = biasws;
  float* biasb_ws = biasws + 4096;
  float* bd_ws = biasws + 8192;

  const int lstm_lds = 98304 + 16384;  // 112KB
  hipFuncSetAttribute((const void*)k_lstm,
                      hipFuncAttributeMaxDynamicSharedMemorySize, lstm_lds);
  void* args[] = {(void*)&xt,       (void*)&WTf,      (void*)&WTb,
                  (void*)&biasf_ws, (void*)&biasb_ws, (void*)&hcat,
                  (void*)&slots0,   (void*)&slots1};
  hipLaunchCooperativeKernel((void*)k_lstm, dim3(256), dim3(512), args,
                             lstm_lds, stream);

  k_dense<<<dim3(256, 16), 256, 0, stream>>>(hcat, WdT, bd_ws, d_out, flag);
}

// Round 2
// 4141.362 us; speedup vs baseline: 1.6046x; 1.6046x over previous
//
#include <hip/hip_runtime.h>
#include <hip/hip_bf16.h>
#include <hip/hip_cooperative_groups.h>

namespace cg = cooperative_groups;

typedef __bf16 bf16x8 __attribute__((ext_vector_type(8)));
typedef float floatx4 __attribute__((ext_vector_type(4)));

#define GLD_LDS16(g, s)                                              \
  __builtin_amdgcn_global_load_lds(                                  \
      (__attribute__((address_space(1))) void*)(g),                  \
      (__attribute__((address_space(3))) void*)(s), 16, 0, 0)

#define MFMA16(a, b, c) __builtin_amdgcn_mfma_f32_16x16x32_bf16(a, b, c, 0, 0, 0)

constexpr int B_ = 128, S_ = 256, E_ = 512, H_ = 1024, V_ = 2048;
constexpr int KC_ = E_ + H_;

// ---- dtype detect (bf16 vs fp32 inputs) ----
__global__ void k_detect(const unsigned short* __restrict__ emb,
                         int* __restrict__ flag) {
  __shared__ int cnt;
  if (threadIdx.x == 0) cnt = 0;
  __syncthreads();
  int local = 0;
  for (int i = threadIdx.x; i < 32768; i += 256) {
    unsigned int u = ((unsigned int)emb[i]) << 16;
    float v = __uint_as_float(u);
    if (!(fabsf(v) < 1.0f)) local++;
  }
  atomicAdd(&cnt, local);
  __syncthreads();
  if (threadIdx.x == 0) flag[0] = (cnt > 256) ? 1 : 0;
}

// ---- biases -> fp32 ws ----
__global__ void k_bias(const void* __restrict__ bfv, const void* __restrict__ bbv,
                       const void* __restrict__ bdv, float* __restrict__ biasws,
                       const int* __restrict__ flag) {
  bool f32 = flag[0] != 0;
  int i = blockIdx.x * 256 + threadIdx.x;
  if (i >= 10240) return;
  const void* src;
  int off;
  if (i < 4096) { src = bfv; off = i; }
  else if (i < 8192) { src = bbv; off = i - 4096; }
  else { src = bdv; off = i - 8192; }
  float v = f32 ? ((const float*)src)[off]
                : __bfloat162float(((const __hip_bfloat16*)src)[off]);
  biasws[i] = v;
}

// ---- gather ----
__global__ void k_gather(const int* __restrict__ tokens, const void* __restrict__ emb,
                         __hip_bfloat16* __restrict__ xt,
                         const int* __restrict__ flag) {
  bool f32 = flag[0] != 0;
  int idx = blockIdx.x * 256 + threadIdx.x;
  int e8 = idx & 63;
  int sb = idx >> 6;
  int s = sb >> 7;
  int b = sb & 127;
  int tok = tokens[b * S_ + s];
  uint4* dst = (uint4*)(xt + (size_t)sb * E_) + e8;
  if (f32) {
    const float* src = (const float*)emb + (size_t)tok * E_ + e8 * 8;
    float4 lo = ((const float4*)src)[0];
    float4 hi = ((const float4*)src)[1];
    __hip_bfloat16 v[8];
    v[0] = __float2bfloat16(lo.x); v[1] = __float2bfloat16(lo.y);
    v[2] = __float2bfloat16(lo.z); v[3] = __float2bfloat16(lo.w);
    v[4] = __float2bfloat16(hi.x); v[5] = __float2bfloat16(hi.y);
    v[6] = __float2bfloat16(hi.z); v[7] = __float2bfloat16(hi.w);
    *dst = *(const uint4*)v;
  } else {
    *dst = ((const uint4*)((const __hip_bfloat16*)emb + (size_t)tok * E_))[e8];
  }
}

// ---- transpose ----
__global__ void k_transpose(const void* __restrict__ in, int K, int N,
                            __hip_bfloat16* __restrict__ out, int ostride,
                            int ocol, const int* __restrict__ flag) {
  bool f32 = flag[0] != 0;
  __shared__ __hip_bfloat16 tile[64][65];
  int n0 = blockIdx.x * 64, k0 = blockIdx.y * 64;
  for (int i = 0; i < 16; ++i) {
    int flat = i * 256 + threadIdx.x;
    int kk = flat >> 6, nn = flat & 63;
    size_t off = (size_t)(k0 + kk) * N + n0 + nn;
    tile[kk][nn] = f32 ? __float2bfloat16(((const float*)in)[off])
                       : ((const __hip_bfloat16*)in)[off];
  }
  __syncthreads();
  for (int i = 0; i < 16; ++i) {
    int flat = i * 256 + threadIdx.x;
    int nn = flat >> 6, kk = flat & 63;
    out[(size_t)(n0 + nn) * ostride + ocol + k0 + kk] = tile[kk][nn];
  }
}

// ---- persistent bidirectional LSTM, weight-stationary, 512 thr/block ----
// 256 blocks: 0..127 fwd (tanh), 128..255 bwd (relu). Block owns 8 h-units
// (N=32 z-cols). Weights [32][1536] in LDS fragment order. 8 waves, wave
// tile M16xN32. Slot-array barrier.
// FENCE-FREE PROTOCOL (round 2): h stores are agent-scope write-through
// atomics; h loads are sc0+sc1 cache-bypass reads from the coherence point.
// No __threadfence -> L2 never written-back/invalidated per step, so the
// x-panel and other read-only data stay L2-warm across all 256 steps.
// Release order: h stores drain at the __syncthreads (vmcnt(0)) before the
// slot signal. Acquire: poll load + bypass h loads never consult stale L1/L2.
__global__ void __launch_bounds__(512, 2)
k_lstm(const __hip_bfloat16* __restrict__ xt,
       const __hip_bfloat16* __restrict__ WTf,
       const __hip_bfloat16* __restrict__ WTb,
       const float* __restrict__ biasf, const float* __restrict__ biasb,
       __hip_bfloat16* __restrict__ hcat, int* __restrict__ slots0,
       int* __restrict__ slots1) {
  extern __shared__ __align__(16) unsigned char smem[];
  __hip_bfloat16* Blds = (__hip_bfloat16*)smem;  // 96 frags x 1KB
  float* ztf = (float*)(smem + 98304);           // 16 frags x 1KB

  const int tid = threadIdx.x, lane = tid & 63, wave = tid >> 6;
  const int dir = blockIdx.x >> 7;
  const int nb = blockIdx.x & 127;
  const int j0 = nb * 8;
  const __hip_bfloat16* WT = dir ? WTb : WTf;
  const float* bias = dir ? biasb : biasf;
  int* slots = dir ? slots1 : slots0;

  // stage weights (fragment order); 12 frags per wave
  for (int f = wave; f < 96; f += 8) {
    int kc = f >> 1, j = f & 1;
    int c = j * 16 + (lane & 15);
    int row = (c >> 3) * H_ + j0 + (c & 7);
    const __hip_bfloat16* src =
        WT + (size_t)row * KC_ + kc * 32 + ((lane >> 4) * 8);
    GLD_LDS16(src, (char*)Blds + (size_t)f * 1024);
  }

  const int jj = tid & 7;
  const int erow = tid >> 3;  // 0..63
  const float bi = bias[j0 + jj];
  const float bf2 = bias[H_ + j0 + jj];
  const float bg = bias[2 * H_ + j0 + jj];
  const float bo = bias[3 * H_ + j0 + jj];
  float creg[2] = {0.f, 0.f};

  const int m0 = wave * 16 + (lane & 15);
  const int k8 = (lane >> 4) * 8;
  __syncthreads();  // drains weight staging

  floatx4 acc[2];
  {  // x-part for t=0
    const int t_in = dir ? (S_ - 1) : 0;
    const __hip_bfloat16* xb =
        xt + (size_t)t_in * B_ * E_ + (size_t)m0 * E_ + k8;
    acc[0] = (floatx4)(0.f);
    acc[1] = (floatx4)(0.f);
#pragma unroll 8
    for (int kc = 0; kc < 16; ++kc) {
      bf16x8 a = *(const bf16x8*)(xb + kc * 32);
      bf16x8 b0 = *(const bf16x8*)((char*)Blds + (kc * 2 + 0) * 1024 + lane * 16);
      bf16x8 b1 = *(const bf16x8*)((char*)Blds + (kc * 2 + 1) * 1024 + lane * 16);
      acc[0] = MFMA16(a, b0, acc[0]);
      acc[1] = MFMA16(a, b1, acc[1]);
    }
  }

  for (int t = 0; t < S_; ++t) {
    const int t_in = dir ? (S_ - 1 - t) : t;
    const int t_prev = dir ? (t_in + 1) : (t_in - 1);

    if (t > 0) {
      if (wave == 0) {  // wait: all 128 slots >= t (parallel poll)
        while (true) {
          int v0 = __hip_atomic_load(slots + lane, __ATOMIC_RELAXED,
                                     __HIP_MEMORY_SCOPE_AGENT);
          int v1 = __hip_atomic_load(slots + 64 + lane, __ATOMIC_RELAXED,
                                     __HIP_MEMORY_SCOPE_AGENT);
          if (__all(v0 >= t && v1 >= t)) break;
          __builtin_amdgcn_s_sleep(1);
        }
      }
      __syncthreads();
      const char* hb = (const char*)(hcat + (size_t)t_prev * B_ * 2 * H_ +
                                     dir * H_ + (size_t)m0 * 2 * H_ + k8);
      // cache-bypass loads straight from the coherence point (no acquire
      // fence needed; L1/L2 never consulted -> never stale)
      bf16x8 ha[32];
#pragma unroll
      for (int kc = 0; kc < 32; ++kc) {
        asm volatile("global_load_dwordx4 %0, %1, off sc0 sc1"
                     : "=v"(ha[kc])
                     : "v"(hb + (size_t)kc * 64));
      }
      asm volatile("s_waitcnt vmcnt(0)" ::: "memory");
      __builtin_amdgcn_sched_barrier(0);
#pragma unroll
      for (int kc = 0; kc < 32; ++kc) {
        bf16x8 b0 =
            *(const bf16x8*)((char*)Blds + ((16 + kc) * 2 + 0) * 1024 + lane * 16);
        bf16x8 b1 =
            *(const bf16x8*)((char*)Blds + ((16 + kc) * 2 + 1) * 1024 + lane * 16);
        acc[0] = MFMA16(ha[kc], b0, acc[0]);
        acc[1] = MFMA16(ha[kc], b1, acc[1]);
      }
    }

    // acc -> LDS fragment order
    *(floatx4*)((char*)ztf + (wave * 2 + 0) * 1024 + lane * 16) = acc[0];
    *(floatx4*)((char*)ztf + (wave * 2 + 1) * 1024 + lane * 16) = acc[1];
    __syncthreads();

    __hip_bfloat16* hout =
        hcat + (size_t)t_in * B_ * 2 * H_ + dir * H_ + j0 + jj;
#pragma unroll
    for (int q = 0; q < 2; ++q) {
      int b_ = erow + q * 64;
      int w = b_ >> 4, mm = b_ & 15;
      float z[4];
#pragma unroll
      for (int g = 0; g < 4; ++g) {
        int c = g * 8 + jj;
        z[g] = ztf[(w * 2 + (c >> 4)) * 256 + ((c & 15) + 16 * (mm >> 2)) * 4 +
                   (mm & 3)];
      }
      float iv = 1.f / (1.f + __expf(-(z[0] + bi)));
      float fv = 1.f / (1.f + __expf(-(z[1] + bf2)));
      float ov = 1.f / (1.f + __expf(-(z[3] + bo)));
      float zg = z[2] + bg;
      float gv = dir ? fmaxf(zg, 0.f) : (1.f - 2.f / (__expf(2.f * zg) + 1.f));
      float c_ = fv * creg[q] + iv * gv;
      creg[q] = c_;
      float hv = dir ? (ov * fmaxf(c_, 0.f))
                     : (ov * (1.f - 2.f / (__expf(2.f * c_) + 1.f)));
      // write-through (agent scope) store: visible at coherence point once
      // vmcnt retires; no L2 writeback fence needed
      unsigned short hbits =
          __builtin_bit_cast(unsigned short, __float2bfloat16(hv));
      __hip_atomic_store((unsigned short*)(hout + (size_t)b_ * 2 * H_), hbits,
                         __ATOMIC_RELAXED, __HIP_MEMORY_SCOPE_AGENT);
    }
    __syncthreads();  // all h stores drained (vmcnt(0) at barrier)

    if (tid == 0) {
      __hip_atomic_store(slots + nb, t + 1, __ATOMIC_RELAXED,
                         __HIP_MEMORY_SCOPE_AGENT);
    }

    if (t + 1 < S_) {  // x-part for next step: hides barrier wait
      const int tn = dir ? (S_ - 2 - t) : (t + 1);
      const __hip_bfloat16* xb =
          xt + (size_t)tn * B_ * E_ + (size_t)m0 * E_ + k8;
      acc[0] = (floatx4)(0.f);
      acc[1] = (floatx4)(0.f);
#pragma unroll 8
      for (int kc = 0; kc < 16; ++kc) {
        bf16x8 a = *(const bf16x8*)(xb + kc * 32);
        bf16x8 b0 =
            *(const bf16x8*)((char*)Blds + (kc * 2 + 0) * 1024 + lane * 16);
        bf16x8 b1 =
            *(const bf16x8*)((char*)Blds + (kc * 2 + 1) * 1024 + lane * 16);
        acc[0] = MFMA16(a, b0, acc[0]);
        acc[1] = MFMA16(a, b1, acc[1]);
      }
    }
  }
}

// ---- dense: out[b][s][v] = hcat[s][b][:] @ Wd + bd ----
__global__ void __launch_bounds__(256, 1)
k_dense(const __hip_bfloat16* __restrict__ hcat,
        const __hip_bfloat16* __restrict__ WdT, const float* __restrict__ bd,
        void* __restrict__ outv, const int* __restrict__ flag) {
  bool f32 = flag[0] != 0;
  __shared__ __align__(16) unsigned char smem[16384];
  __hip_bfloat16* At = (__hip_bfloat16*)smem;
  __hip_bfloat16* Bt = (__hip_bfloat16*)(smem + 8192);
  const int tid = threadIdx.x, lane = tid & 63, wave = tid >> 6;
  const int wr = wave >> 1, wc = wave & 1;
  const int r0 = blockIdx.x * 128;
  const int n0 = blockIdx.y * 128;

  floatx4 acc[4][4] = {};
  int arow[2], akoff[2];
  for (int q = 0; q < 2; ++q) {
    int flat = (wave * 2 + q) * 1024 + lane * 16;
    arow[q] = flat >> 6;
    akoff[q] = (flat & 63) >> 1;
  }

  for (int kc = 0; kc < 64; ++kc) {
    for (int q = 0; q < 2; ++q) {
      const __hip_bfloat16* srcA =
          hcat + (size_t)(r0 + arow[q]) * 2048 + kc * 32 + akoff[q];
      GLD_LDS16(srcA, At + (wave * 2 + q) * 512);
      const __hip_bfloat16* srcB =
          WdT + (size_t)(n0 + arow[q]) * 2048 + kc * 32 + akoff[q];
      GLD_LDS16(srcB, Bt + (wave * 2 + q) * 512);
    }
    __syncthreads();
    bf16x8 a[4], b[4];
    const int k8 = (lane >> 4) * 8;
    for (int i = 0; i < 4; ++i) {
      int m = wr * 64 + i * 16 + (lane & 15);
      a[i] = *(const bf16x8*)((const char*)At + m * 64 + k8 * 2);
    }
    for (int j = 0; j < 4; ++j) {
      int n = wc * 64 + j * 16 + (lane & 15);
      b[j] = *(const bf16x8*)((const char*)Bt + n * 64 + k8 * 2);
    }
    for (int i = 0; i < 4; ++i)
      for (int j = 0; j < 4; ++j)
        acc[i][j] = MFMA16(a[i], b[j], acc[i][j]);
    __syncthreads();
  }

  for (int j = 0; j < 4; ++j) {
    int n = n0 + wc * 64 + j * 16 + (lane & 15);
    float bdv = bd[n];
    for (int i = 0; i < 4; ++i)
      for (int r = 0; r < 4; ++r) {
        int m = wr * 64 + i * 16 + (lane >> 4) * 4 + r;
        int row = r0 + m;
        int s = row >> 7, b_ = row & 127;
        size_t off = (size_t)b_ * S_ * V_ + (size_t)s * V_ + n;
        float val = acc[i][j][r] + bdv;
        if (f32)
          ((float*)outv)[off] = val;
        else
          ((__hip_bfloat16*)outv)[off] = __float2bfloat16(val);
      }
  }
}

extern "C" void kernel_launch(void* const* d_in, const int* in_sizes, int n_in,
                              void* d_out, int out_size, void* d_ws,
                              size_t ws_size, hipStream_t stream) {
  const int* tokens = (const int*)d_in[0];
  const void* emb = d_in[1];
  const void* Wf = d_in[2];
  const void* Uf = d_in[3];
  const void* bfv = d_in[4];
  const void* Wb = d_in[5];
  const void* Ub = d_in[6];
  const void* bbv = d_in[7];
  const void* Wd = d_in[8];
  const void* bd = d_in[9];

  char* ws = (char*)d_ws;
  int* flag = (int*)ws;                      // 4B @ 0
  int* slots0 = (int*)(ws + 128);            // 128 ints
  int* slots1 = (int*)(ws + 1152);           // 128 ints
  float* biasws = (float*)(ws + 4096);       // 10240 f32
  __hip_bfloat16* WTf = (__hip_bfloat16*)(ws + 4096 + 40960);
  __hip_bfloat16* WTb = WTf + (size_t)4096 * 1536;
  __hip_bfloat16* WdT = WTb + (size_t)4096 * 1536;
  __hip_bfloat16* xt = WdT + (size_t)2048 * 2048;
  __hip_bfloat16* hcat = xt + (size_t)S_ * B_ * E_;  // [256][128][2048]

  hipMemsetAsync(ws + 128, 0, 4096 - 128, stream);
  k_detect<<<1, 256, 0, stream>>>((const unsigned short*)emb, flag);
  k_bias<<<40, 256, 0, stream>>>(bfv, bbv, bd, biasws, flag);
  k_gather<<<8192, 256, 0, stream>>>(tokens, emb, xt, flag);
  k_transpose<<<dim3(64, 8), 256, 0, stream>>>(Wf, 512, 4096, WTf, KC_, 0, flag);
  k_transpose<<<dim3(64, 16), 256, 0, stream>>>(Uf, 1024, 4096, WTf, KC_, 512, flag);
  k_transpose<<<dim3(64, 8), 256, 0, stream>>>(Wb, 512, 4096, WTb, KC_, 0, flag);
  k_transpose<<<dim3(64, 16), 256, 0, stream>>>(Ub, 1024, 4096, WTb, KC_, 512, flag);
  k_transpose<<<dim3(32, 32), 256, 0, stream>>>(Wd, 2048, 2048, WdT, 2048, 0, flag);

  float* biasf_ws = biasws;
  float* biasb_ws = biasws + 4096;
  float* bd_ws = biasws + 8192;

  const int lstm_lds = 98304 + 16384;  // 112KB
  hipFuncSetAttribute((const void*)k_lstm,
                      hipFuncAttributeMaxDynamicSharedMemorySize, lstm_lds);
  void* args[] = {(void*)&xt,       (void*)&WTf,      (void*)&WTb,
                  (void*)&biasf_ws, (void*)&biasb_ws, (void*)&hcat,
                  (void*)&slots0,   (void*)&slots1};
  hipLaunchCooperativeKernel((void*)k_lstm, dim3(256), dim3(512), args,
                             lstm_lds, stream);

  k_dense<<<dim3(256, 16), 256, 0, stream>>>(hcat, WdT, bd_ws, d_out, flag);
}

// Round 3
// 3862.537 us; speedup vs baseline: 1.7205x; 1.0722x over previous
//
#include <hip/hip_runtime.h>
#include <hip/hip_bf16.h>
#include <hip/hip_cooperative_groups.h>

namespace cg = cooperative_groups;

typedef __bf16 bf16x8 __attribute__((ext_vector_type(8)));
typedef float floatx4 __attribute__((ext_vector_type(4)));

#define GLD_LDS16(g, s)                                              \
  __builtin_amdgcn_global_load_lds(                                  \
      (__attribute__((address_space(1))) void*)(g),                  \
      (__attribute__((address_space(3))) void*)(s), 16, 0, 0)

#define MFMA16(a, b, c) __builtin_amdgcn_mfma_f32_16x16x32_bf16(a, b, c, 0, 0, 0)

constexpr int B_ = 128, S_ = 256, E_ = 512, H_ = 1024, V_ = 2048;
constexpr int KC_ = E_ + H_;

// ---- dtype detect (bf16 vs fp32 inputs) ----
__global__ void k_detect(const unsigned short* __restrict__ emb,
                         int* __restrict__ flag) {
  __shared__ int cnt;
  if (threadIdx.x == 0) cnt = 0;
  __syncthreads();
  int local = 0;
  for (int i = threadIdx.x; i < 32768; i += 256) {
    unsigned int u = ((unsigned int)emb[i]) << 16;
    float v = __uint_as_float(u);
    if (!(fabsf(v) < 1.0f)) local++;
  }
  atomicAdd(&cnt, local);
  __syncthreads();
  if (threadIdx.x == 0) flag[0] = (cnt > 256) ? 1 : 0;
}

// ---- biases -> fp32 ws ----
__global__ void k_bias(const void* __restrict__ bfv, const void* __restrict__ bbv,
                       const void* __restrict__ bdv, float* __restrict__ biasws,
                       const int* __restrict__ flag) {
  bool f32 = flag[0] != 0;
  int i = blockIdx.x * 256 + threadIdx.x;
  if (i >= 10240) return;
  const void* src;
  int off;
  if (i < 4096) { src = bfv; off = i; }
  else if (i < 8192) { src = bbv; off = i - 4096; }
  else { src = bdv; off = i - 8192; }
  float v = f32 ? ((const float*)src)[off]
                : __bfloat162float(((const __hip_bfloat16*)src)[off]);
  biasws[i] = v;
}

// ---- gather ----
__global__ void k_gather(const int* __restrict__ tokens, const void* __restrict__ emb,
                         __hip_bfloat16* __restrict__ xt,
                         const int* __restrict__ flag) {
  bool f32 = flag[0] != 0;
  int idx = blockIdx.x * 256 + threadIdx.x;
  int e8 = idx & 63;
  int sb = idx >> 6;
  int s = sb >> 7;
  int b = sb & 127;
  int tok = tokens[b * S_ + s];
  uint4* dst = (uint4*)(xt + (size_t)sb * E_) + e8;
  if (f32) {
    const float* src = (const float*)emb + (size_t)tok * E_ + e8 * 8;
    float4 lo = ((const float4*)src)[0];
    float4 hi = ((const float4*)src)[1];
    __hip_bfloat16 v[8];
    v[0] = __float2bfloat16(lo.x); v[1] = __float2bfloat16(lo.y);
    v[2] = __float2bfloat16(lo.z); v[3] = __float2bfloat16(lo.w);
    v[4] = __float2bfloat16(hi.x); v[5] = __float2bfloat16(hi.y);
    v[6] = __float2bfloat16(hi.z); v[7] = __float2bfloat16(hi.w);
    *dst = *(const uint4*)v;
  } else {
    *dst = ((const uint4*)((const __hip_bfloat16*)emb + (size_t)tok * E_))[e8];
  }
}

// ---- transpose ----
__global__ void k_transpose(const void* __restrict__ in, int K, int N,
                            __hip_bfloat16* __restrict__ out, int ostride,
                            int ocol, const int* __restrict__ flag) {
  bool f32 = flag[0] != 0;
  __shared__ __hip_bfloat16 tile[64][65];
  int n0 = blockIdx.x * 64, k0 = blockIdx.y * 64;
  for (int i = 0; i < 16; ++i) {
    int flat = i * 256 + threadIdx.x;
    int kk = flat >> 6, nn = flat & 63;
    size_t off = (size_t)(k0 + kk) * N + n0 + nn;
    tile[kk][nn] = f32 ? __float2bfloat16(((const float*)in)[off])
                       : ((const __hip_bfloat16*)in)[off];
  }
  __syncthreads();
  for (int i = 0; i < 16; ++i) {
    int flat = i * 256 + threadIdx.x;
    int nn = flat >> 6, kk = flat & 63;
    out[(size_t)(n0 + nn) * ostride + ocol + k0 + kk] = tile[kk][nn];
  }
}

// ---- persistent bidirectional LSTM, weight-stationary, 512 thr/block ----
// 256 blocks: 0..127 fwd (tanh), 128..255 bwd (relu). Block owns 8 h-units
// (N=32 z-cols). Weights [32][1536] in LDS fragment order. 8 waves, wave
// tile M16xN32. Slot-array barrier.
// Round-3 protocol: producer h stores remain agent-scope write-through
// atomics (visible at MALL before slot signal; drained at the barrier).
// Consumer h loads are NORMAL CACHED loads: within a run each hcat[t] line
// is written once and only read after the signal, so no consumer L2 can
// hold a stale copy -> no acquire needed, and the 32 blocks/XCD share one
// L2 fill of the 2x256KB h panels instead of each re-pulling from MALL.
__global__ void __launch_bounds__(512, 2)
k_lstm(const __hip_bfloat16* __restrict__ xt,
       const __hip_bfloat16* __restrict__ WTf,
       const __hip_bfloat16* __restrict__ WTb,
       const float* __restrict__ biasf, const float* __restrict__ biasb,
       __hip_bfloat16* __restrict__ hcat, int* __restrict__ slots0,
       int* __restrict__ slots1) {
  extern __shared__ __align__(16) unsigned char smem[];
  __hip_bfloat16* Blds = (__hip_bfloat16*)smem;  // 96 frags x 1KB
  float* ztf = (float*)(smem + 98304);           // 16 frags x 1KB

  const int tid = threadIdx.x, lane = tid & 63, wave = tid >> 6;
  const int dir = blockIdx.x >> 7;
  const int nb = blockIdx.x & 127;
  const int j0 = nb * 8;
  const __hip_bfloat16* WT = dir ? WTb : WTf;
  const float* bias = dir ? biasb : biasf;
  int* slots = dir ? slots1 : slots0;

  // stage weights (fragment order); 12 frags per wave
  for (int f = wave; f < 96; f += 8) {
    int kc = f >> 1, j = f & 1;
    int c = j * 16 + (lane & 15);
    int row = (c >> 3) * H_ + j0 + (c & 7);
    const __hip_bfloat16* src =
        WT + (size_t)row * KC_ + kc * 32 + ((lane >> 4) * 8);
    GLD_LDS16(src, (char*)Blds + (size_t)f * 1024);
  }

  const int jj = tid & 7;
  const int erow = tid >> 3;  // 0..63
  const float bi = bias[j0 + jj];
  const float bf2 = bias[H_ + j0 + jj];
  const float bg = bias[2 * H_ + j0 + jj];
  const float bo = bias[3 * H_ + j0 + jj];
  float creg[2] = {0.f, 0.f};

  const int m0 = wave * 16 + (lane & 15);
  const int k8 = (lane >> 4) * 8;
  __syncthreads();  // drains weight staging

  floatx4 acc[2];
  {  // x-part for t=0
    const int t_in = dir ? (S_ - 1) : 0;
    const __hip_bfloat16* xb =
        xt + (size_t)t_in * B_ * E_ + (size_t)m0 * E_ + k8;
    acc[0] = (floatx4)(0.f);
    acc[1] = (floatx4)(0.f);
#pragma unroll 8
    for (int kc = 0; kc < 16; ++kc) {
      bf16x8 a = *(const bf16x8*)(xb + kc * 32);
      bf16x8 b0 = *(const bf16x8*)((char*)Blds + (kc * 2 + 0) * 1024 + lane * 16);
      bf16x8 b1 = *(const bf16x8*)((char*)Blds + (kc * 2 + 1) * 1024 + lane * 16);
      acc[0] = MFMA16(a, b0, acc[0]);
      acc[1] = MFMA16(a, b1, acc[1]);
    }
  }

  for (int t = 0; t < S_; ++t) {
    const int t_in = dir ? (S_ - 1 - t) : t;
    const int t_prev = dir ? (t_in + 1) : (t_in - 1);

    if (t > 0) {
      if (wave == 0) {  // wait: all 128 slots >= t (parallel poll)
        while (true) {
          int v0 = __hip_atomic_load(slots + lane, __ATOMIC_RELAXED,
                                     __HIP_MEMORY_SCOPE_AGENT);
          int v1 = __hip_atomic_load(slots + 64 + lane, __ATOMIC_RELAXED,
                                     __HIP_MEMORY_SCOPE_AGENT);
          if (__all(v0 >= t && v1 >= t)) break;
          __builtin_amdgcn_s_sleep(1);
        }
      }
      __syncthreads();
      const __hip_bfloat16* hb = hcat + (size_t)t_prev * B_ * 2 * H_ +
                                 dir * H_ + (size_t)m0 * 2 * H_ + k8;
      // normal cached loads: L2 of each XCD is filled once, 31 sibling
      // blocks hit. No stale-line hazard (lines written once, read after
      // signal, never touched before).
#pragma unroll 8
      for (int kc = 0; kc < 32; ++kc) {
        bf16x8 a = *(const bf16x8*)(hb + (size_t)kc * 32);
        bf16x8 b0 =
            *(const bf16x8*)((char*)Blds + ((16 + kc) * 2 + 0) * 1024 + lane * 16);
        bf16x8 b1 =
            *(const bf16x8*)((char*)Blds + ((16 + kc) * 2 + 1) * 1024 + lane * 16);
        acc[0] = MFMA16(a, b0, acc[0]);
        acc[1] = MFMA16(a, b1, acc[1]);
      }
    }

    // acc -> LDS fragment order
    *(floatx4*)((char*)ztf + (wave * 2 + 0) * 1024 + lane * 16) = acc[0];
    *(floatx4*)((char*)ztf + (wave * 2 + 1) * 1024 + lane * 16) = acc[1];
    __syncthreads();

    __hip_bfloat16* hout =
        hcat + (size_t)t_in * B_ * 2 * H_ + dir * H_ + j0 + jj;
#pragma unroll
    for (int q = 0; q < 2; ++q) {
      int b_ = erow + q * 64;
      int w = b_ >> 4, mm = b_ & 15;
      float z[4];
#pragma unroll
      for (int g = 0; g < 4; ++g) {
        int c = g * 8 + jj;
        z[g] = ztf[(w * 2 + (c >> 4)) * 256 + ((c & 15) + 16 * (mm >> 2)) * 4 +
                   (mm & 3)];
      }
      float iv = 1.f / (1.f + __expf(-(z[0] + bi)));
      float fv = 1.f / (1.f + __expf(-(z[1] + bf2)));
      float ov = 1.f / (1.f + __expf(-(z[3] + bo)));
      float zg = z[2] + bg;
      float gv = dir ? fmaxf(zg, 0.f) : (1.f - 2.f / (__expf(2.f * zg) + 1.f));
      float c_ = fv * creg[q] + iv * gv;
      creg[q] = c_;
      float hv = dir ? (ov * fmaxf(c_, 0.f))
                     : (ov * (1.f - 2.f / (__expf(2.f * c_) + 1.f)));
      // write-through (agent scope) store: visible at coherence point once
      // vmcnt retires; no L2 writeback fence needed
      unsigned short hbits =
          __builtin_bit_cast(unsigned short, __float2bfloat16(hv));
      __hip_atomic_store((unsigned short*)(hout + (size_t)b_ * 2 * H_), hbits,
                         __ATOMIC_RELAXED, __HIP_MEMORY_SCOPE_AGENT);
    }
    __syncthreads();  // all h stores drained (vmcnt(0) at barrier)

    if (tid == 0) {
      __hip_atomic_store(slots + nb, t + 1, __ATOMIC_RELAXED,
                         __HIP_MEMORY_SCOPE_AGENT);
    }

    if (t + 1 < S_) {  // x-part for next step: hides barrier wait
      const int tn = dir ? (S_ - 2 - t) : (t + 1);
      const __hip_bfloat16* xb =
          xt + (size_t)tn * B_ * E_ + (size_t)m0 * E_ + k8;
      acc[0] = (floatx4)(0.f);
      acc[1] = (floatx4)(0.f);
#pragma unroll 8
      for (int kc = 0; kc < 16; ++kc) {
        bf16x8 a = *(const bf16x8*)(xb + kc * 32);
        bf16x8 b0 =
            *(const bf16x8*)((char*)Blds + (kc * 2 + 0) * 1024 + lane * 16);
        bf16x8 b1 =
            *(const bf16x8*)((char*)Blds + (kc * 2 + 1) * 1024 + lane * 16);
        acc[0] = MFMA16(a, b0, acc[0]);
        acc[1] = MFMA16(a, b1, acc[1]);
      }
    }
  }
}

// ---- dense: out[b][s][v] = hcat[s][b][:] @ Wd + bd ----
__global__ void __launch_bounds__(256, 1)
k_dense(const __hip_bfloat16* __restrict__ hcat,
        const __hip_bfloat16* __restrict__ WdT, const float* __restrict__ bd,
        void* __restrict__ outv, const int* __restrict__ flag) {
  bool f32 = flag[0] != 0;
  __shared__ __align__(16) unsigned char smem[16384];
  __hip_bfloat16* At = (__hip_bfloat16*)smem;
  __hip_bfloat16* Bt = (__hip_bfloat16*)(smem + 8192);
  const int tid = threadIdx.x, lane = tid & 63, wave = tid >> 6;
  const int wr = wave >> 1, wc = wave & 1;
  const int r0 = blockIdx.x * 128;
  const int n0 = blockIdx.y * 128;

  floatx4 acc[4][4] = {};
  int arow[2], akoff[2];
  for (int q = 0; q < 2; ++q) {
    int flat = (wave * 2 + q) * 1024 + lane * 16;
    arow[q] = flat >> 6;
    akoff[q] = (flat & 63) >> 1;
  }

  for (int kc = 0; kc < 64; ++kc) {
    for (int q = 0; q < 2; ++q) {
      const __hip_bfloat16* srcA =
          hcat + (size_t)(r0 + arow[q]) * 2048 + kc * 32 + akoff[q];
      GLD_LDS16(srcA, At + (wave * 2 + q) * 512);
      const __hip_bfloat16* srcB =
          WdT + (size_t)(n0 + arow[q]) * 2048 + kc * 32 + akoff[q];
      GLD_LDS16(srcB, Bt + (wave * 2 + q) * 512);
    }
    __syncthreads();
    bf16x8 a[4], b[4];
    const int k8 = (lane >> 4) * 8;
    for (int i = 0; i < 4; ++i) {
      int m = wr * 64 + i * 16 + (lane & 15);
      a[i] = *(const bf16x8*)((const char*)At + m * 64 + k8 * 2);
    }
    for (int j = 0; j < 4; ++j) {
      int n = wc * 64 + j * 16 + (lane & 15);
      b[j] = *(const bf16x8*)((const char*)Bt + n * 64 + k8 * 2);
    }
    for (int i = 0; i < 4; ++i)
      for (int j = 0; j < 4; ++j)
        acc[i][j] = MFMA16(a[i], b[j], acc[i][j]);
    __syncthreads();
  }

  for (int j = 0; j < 4; ++j) {
    int n = n0 + wc * 64 + j * 16 + (lane & 15);
    float bdv = bd[n];
    for (int i = 0; i < 4; ++i)
      for (int r = 0; r < 4; ++r) {
        int m = wr * 64 + i * 16 + (lane >> 4) * 4 + r;
        int row = r0 + m;
        int s = row >> 7, b_ = row & 127;
        size_t off = (size_t)b_ * S_ * V_ + (size_t)s * V_ + n;
        float val = acc[i][j][r] + bdv;
        if (f32)
          ((float*)outv)[off] = val;
        else
          ((__hip_bfloat16*)outv)[off] = __float2bfloat16(val);
      }
  }
}

extern "C" void kernel_launch(void* const* d_in, const int* in_sizes, int n_in,
                              void* d_out, int out_size, void* d_ws,
                              size_t ws_size, hipStream_t stream) {
  const int* tokens = (const int*)d_in[0];
  const void* emb = d_in[1];
  const void* Wf = d_in[2];
  const void* Uf = d_in[3];
  const void* bfv = d_in[4];
  const void* Wb = d_in[5];
  const void* Ub = d_in[6];
  const void* bbv = d_in[7];
  const void* Wd = d_in[8];
  const void* bd = d_in[9];

  char* ws = (char*)d_ws;
  int* flag = (int*)ws;                      // 4B @ 0
  int* slots0 = (int*)(ws + 128);            // 128 ints
  int* slots1 = (int*)(ws + 1152);           // 128 ints
  float* biasws = (float*)(ws + 4096);       // 10240 f32
  __hip_bfloat16* WTf = (__hip_bfloat16*)(ws + 4096 + 40960);
  __hip_bfloat16* WTb = WTf + (size_t)4096 * 1536;
  __hip_bfloat16* WdT = WTb + (size_t)4096 * 1536;
  __hip_bfloat16* xt = WdT + (size_t)2048 * 2048;
  __hip_bfloat16* hcat = xt + (size_t)S_ * B_ * E_;  // [256][128][2048]

  hipMemsetAsync(ws + 128, 0, 4096 - 128, stream);
  k_detect<<<1, 256, 0, stream>>>((const unsigned short*)emb, flag);
  k_bias<<<40, 256, 0, stream>>>(bfv, bbv, bd, biasws, flag);
  k_gather<<<8192, 256, 0, stream>>>(tokens, emb, xt, flag);
  k_transpose<<<dim3(64, 8), 256, 0, stream>>>(Wf, 512, 4096, WTf, KC_, 0, flag);
  k_transpose<<<dim3(64, 16), 256, 0, stream>>>(Uf, 1024, 4096, WTf, KC_, 512, flag);
  k_transpose<<<dim3(64, 8), 256, 0, stream>>>(Wb, 512, 4096, WTb, KC_, 0, flag);
  k_transpose<<<dim3(64, 16), 256, 0, stream>>>(Ub, 1024, 4096, WTb, KC_, 512, flag);
  k_transpose<<<dim3(32, 32), 256, 0, stream>>>(Wd, 2048, 2048, WdT, 2048, 0, flag);

  float* biasf_ws = biasws;
  float* biasb_ws = biasws + 4096;
  float* bd_ws = biasws + 8192;

  const int lstm_lds = 98304 + 16384;  // 112KB
  hipFuncSetAttribute((const void*)k_lstm,
                      hipFuncAttributeMaxDynamicSharedMemorySize, lstm_lds);
  void* args[] = {(void*)&xt,       (void*)&WTf,      (void*)&WTb,
                  (void*)&biasf_ws, (void*)&biasb_ws, (void*)&hcat,
                  (void*)&slots0,   (void*)&slots1};
  hipLaunchCooperativeKernel((void*)k_lstm, dim3(256), dim3(512), args,
                             lstm_lds, stream);

  k_dense<<<dim3(256, 16), 256, 0, stream>>>(hcat, WdT, bd_ws, d_out, flag);
}